// Round 13
// baseline (236.295 us; speedup 1.0000x reference)
//
#include <hip/hip_runtime.h>

// LightGCN 3-hop propagation, D=64, bf16 features / fp32 accumulate.
// R13: (1) spmm: uniform 16-batch loop with scalar val-masking for the row
// tail — a deg-23 row was 5 serial round-trips (16/4/1/1/1), now 2. Edges
// live in SGPRs (wave-uniform addresses), so masking is s_cselect on val;
// over-read crosses into the next row's segment (valid; +16 zero-edge global
// pad). (2) sort_bkt: one 256-thread block per bucket (4-wave co-op with
// barriers) instead of one wave -> 4x MLP. Rest unchanged from R11.

#define NBUCKET 3125     // N=100000 rows, 32 per bucket
#define BSHIFT  5
#define BMASK   31
#define NCHUNK  256      // edge chunks; E=1.6M -> 6250 edges/chunk

static __device__ __forceinline__ ushort f2bf(float f) {
    unsigned u = __float_as_uint(f);
    unsigned r = (u + 0x7fffu + ((u >> 16) & 1u)) >> 16;   // RNE
    return (ushort)r;
}
static __device__ __forceinline__ float bf2f(ushort b) {
    return __uint_as_float(((unsigned)b) << 16);
}

__global__ __launch_bounds__(256) void f2bf_k(
    const float* __restrict__ in, ushort* __restrict__ out, int n4)
{
    int i = blockIdx.x * blockDim.x + threadIdx.x;
    if (i >= n4) return;
    float4 v = *(const float4*)(in + (long)i * 4);
    ushort4 o;
    o.x = f2bf(v.x); o.y = f2bf(v.y); o.z = f2bf(v.z); o.w = f2bf(v.w);
    *(ushort4*)(out + (long)i * 4) = o;
}

// pass A: per-chunk bucket histogram in LDS (no global atomics); 16 waves
__global__ __launch_bounds__(1024) void count_k(
    const int* __restrict__ rows, int* __restrict__ cnt, int E, int chunkE)
{
    __shared__ unsigned h[NBUCKET];
    int c = blockIdx.x;
    for (int b = threadIdx.x; b < NBUCKET; b += 1024) h[b] = 0u;
    __syncthreads();
    int s = c * chunkE;
    int e = min(s + chunkE, E);
    for (int j = s + (int)threadIdx.x; j < e; j += 1024)
        atomicAdd(&h[rows[j] >> BSHIFT], 1u);
    __syncthreads();
    int* o = cnt + (long)c * NBUCKET;
    for (int b = threadIdx.x; b < NBUCKET; b += 1024) o[b] = (int)h[b];
}

// pass B: per-bucket local exclusive prefix over chunks + bucket totals.
__global__ __launch_bounds__(256) void localscan_k(
    const int* __restrict__ cnt, int* __restrict__ offs,
    int* __restrict__ totals)
{
    int b = blockIdx.x * 256 + threadIdx.x;
    if (b >= NBUCKET) return;
    int run = 0;
    #pragma unroll 8
    for (int c = 0; c < NCHUNK; ++c) {
        long i = (long)c * NBUCKET + b;
        int v = cnt[i];
        offs[i] = run;
        run += v;
    }
    totals[b] = run;
}

// fused exclusive scan over nbucket elements; single block of 1024
__global__ __launch_bounds__(1024) void scan_fused_k(
    const int* __restrict__ totals, int* __restrict__ bucket_start, int nbucket)
{
    __shared__ int sm[1024];
    __shared__ int carry_s;
    if (threadIdx.x == 0) carry_s = 0;
    __syncthreads();
    int ntile = (nbucket + 1023) / 1024;
    for (int t = 0; t < ntile; ++t) {
        int i = t * 1024 + threadIdx.x;
        int v = (i < nbucket) ? totals[i] : 0;
        sm[threadIdx.x] = v;
        __syncthreads();
        for (int off = 1; off < 1024; off <<= 1) {
            int add = (threadIdx.x >= off) ? sm[threadIdx.x - off] : 0;
            __syncthreads();
            sm[threadIdx.x] += add;
            __syncthreads();
        }
        int c0 = carry_s;
        if (i < nbucket) bucket_start[i] = c0 + sm[threadIdx.x] - v;
        __syncthreads();
        if (threadIdx.x == 1023) carry_s = c0 + sm[1023];
        __syncthreads();
    }
    if (threadIdx.x == 0) bucket_start[nbucket] = carry_s;   // == E
}

// pass C: partition edges into bucket segments; LDS cursors only; 16 waves.
// edge payload: .x = (row&31)<<17 | col  (col < 2^17), .y = val bits
__global__ __launch_bounds__(1024) void scatter3_k(
    const int* __restrict__ rows, const int* __restrict__ cols,
    const float* __restrict__ vals, const int* __restrict__ offs,
    const int* __restrict__ bucket_start,
    int2* __restrict__ edges, int E, int chunkE)
{
    __shared__ int cur[NBUCKET];
    int c = blockIdx.x;
    const int* o = offs + (long)c * NBUCKET;
    for (int b = threadIdx.x; b < NBUCKET; b += 1024)
        cur[b] = o[b] + bucket_start[b];
    __syncthreads();
    int s = c * chunkE;
    int e = min(s + chunkE, E);
    for (int j = s + (int)threadIdx.x; j < e; j += 1024) {
        int r = rows[j];
        int pos = atomicAdd(&cur[r >> BSHIFT], 1);
        edges[pos] = make_int2(((r & BMASK) << 17) | cols[j],
                               __float_as_int(vals[j]));
    }
}

// pass D: per-bucket counting sort, one 256-thread block per bucket.
// Also writes 16 zero-val pad edges after the last bucket (for spmm's
// masked over-read).
__global__ __launch_bounds__(256) void sort_bkt_k(
    const int* __restrict__ bucket_start, const int2* __restrict__ edges_in,
    int2* __restrict__ edges_out, int* __restrict__ row_start, int nbucket)
{
    __shared__ int cnt_s[32];
    __shared__ int cur_s[32];
    int bk = blockIdx.x;
    int t = (int)threadIdx.x;
    int s = bucket_start[bk];
    int e = bucket_start[bk + 1];
    if (t < 32) cnt_s[t] = 0;
    __syncthreads();
    for (int j = s + t; j < e; j += 256)
        atomicAdd(&cnt_s[(unsigned)edges_in[j].x >> 17], 1);
    __syncthreads();
    if (t == 0) {
        int run = s;
        #pragma unroll
        for (int r = 0; r < 32; ++r) {
            int c = cnt_s[r];
            cur_s[r] = run;
            row_start[bk * 32 + r] = run;
            run += c;
        }
    }
    __syncthreads();
    for (int j = s + t; j < e; j += 256) {
        int2 ed = edges_in[j];
        int pos = atomicAdd(&cur_s[(unsigned)ed.x >> 17], 1);
        edges_out[pos] = ed;
    }
    if (bk == nbucket - 1) {
        if (t == 0) row_start[nbucket * 32] = e;   // == E
        if (t < 16) edges_out[e + t] = make_int2(0, 0);  // zero-val pad
    }
}

// product with scalar tail-mask: chains past the row end get val = 0
#define GMAM(k) float p##k = ((j + k) < e ? __int_as_float(ee##k.y) : 0.f) * \
    bf2f(x[(long)(ee##k.x & 0x1FFFF) * 64 + d])

// spmm: one wave per row; lane = feature dim; scalar edge stream in SGPRs;
// uniform 16-batch loop, tail masked by zeroing val (exact +0 terms).
__global__ __launch_bounds__(256) void spmm_csr_k(
    const int* __restrict__ row_start, const int2* __restrict__ edges,
    const ushort* __restrict__ x, ushort* __restrict__ y, int N)
{
    int wid = __builtin_amdgcn_readfirstlane((int)(threadIdx.x >> 6));
    int r = blockIdx.x * 4 + wid;
    if (r >= N) return;
    int d = (int)(threadIdx.x & 63);
    int s = row_start[r];      // wave-uniform -> s_load
    int e = row_start[r + 1];
    float a0 = 0.f, a1 = 0.f, a2 = 0.f, a3 = 0.f;
    float a4 = 0.f, a5 = 0.f, a6 = 0.f, a7 = 0.f;
    float a8 = 0.f, a9 = 0.f, a10 = 0.f, a11 = 0.f;
    float a12 = 0.f, a13 = 0.f, a14 = 0.f, a15 = 0.f;
    for (int j = s; j < e; j += 16) {
        int2 ee0  = edges[j];      int2 ee1  = edges[j + 1];
        int2 ee2  = edges[j + 2];  int2 ee3  = edges[j + 3];
        int2 ee4  = edges[j + 4];  int2 ee5  = edges[j + 5];
        int2 ee6  = edges[j + 6];  int2 ee7  = edges[j + 7];
        int2 ee8  = edges[j + 8];  int2 ee9  = edges[j + 9];
        int2 ee10 = edges[j + 10]; int2 ee11 = edges[j + 11];
        int2 ee12 = edges[j + 12]; int2 ee13 = edges[j + 13];
        int2 ee14 = edges[j + 14]; int2 ee15 = edges[j + 15];
        GMAM(0); GMAM(1); GMAM(2); GMAM(3);
        GMAM(4); GMAM(5); GMAM(6); GMAM(7);
        GMAM(8); GMAM(9); GMAM(10); GMAM(11);
        GMAM(12); GMAM(13); GMAM(14); GMAM(15);
        a0 += p0;  a1 += p1;  a2 += p2;  a3 += p3;
        a4 += p4;  a5 += p5;  a6 += p6;  a7 += p7;
        a8 += p8;  a9 += p9;  a10 += p10; a11 += p11;
        a12 += p12; a13 += p13; a14 += p14; a15 += p15;
    }
    float sum = (((a0 + a1) + (a2 + a3)) + ((a4 + a5) + (a6 + a7)))
              + (((a8 + a9) + (a10 + a11)) + ((a12 + a13) + (a14 + a15)));
    y[(long)r * 64 + d] = f2bf(sum);
}

// out[0..2] = 0.25*emb[idx] (hop-0 term), out[3..5] = emb[idx]; float4 lanes
__global__ __launch_bounds__(256) void init_out_k(
    const float* __restrict__ emb, const int* __restrict__ n0,
    const int* __restrict__ n1, const int* __restrict__ n2,
    float* __restrict__ out, int B)
{
    int tid = blockIdx.x * blockDim.x + threadIdx.x;
    int total = 3 * B * 16;                 // float4 granularity
    if (tid >= total) return;
    int arr = tid / (B * 16);
    int rem = tid - arr * (B * 16);
    int b = rem >> 4;
    int d4 = rem & 15;
    const int* __restrict__ idx = (arr == 0) ? n0 : ((arr == 1) ? n1 : n2);
    float4 v = *(const float4*)(emb + (long)idx[b] * 64 + d4 * 4);
    float4 q = make_float4(0.25f * v.x, 0.25f * v.y, 0.25f * v.z, 0.25f * v.w);
    *(float4*)(out + (long)arr * B * 64 + (long)rem * 4) = q;
    *(float4*)(out + (long)(arr + 3) * B * 64 + (long)rem * 4) = v;
}

// pooled += 0.25 * agg_bf16[idx]
__global__ __launch_bounds__(256) void gather_add_k(
    const ushort* __restrict__ agg, const int* __restrict__ n0,
    const int* __restrict__ n1, const int* __restrict__ n2,
    float* __restrict__ out, int B)
{
    int tid = blockIdx.x * blockDim.x + threadIdx.x;
    int total = 3 * B * 16;
    if (tid >= total) return;
    int arr = tid / (B * 16);
    int rem = tid - arr * (B * 16);
    int b = rem >> 4;
    int d4 = rem & 15;
    const int* __restrict__ idx = (arr == 0) ? n0 : ((arr == 1) ? n1 : n2);
    ushort4 v = *(const ushort4*)(agg + (long)idx[b] * 64 + d4 * 4);
    float* o = out + (long)arr * B * 64 + (long)rem * 4;
    float4 cur = *(float4*)o;
    cur.x += 0.25f * bf2f(v.x); cur.y += 0.25f * bf2f(v.y);
    cur.z += 0.25f * bf2f(v.z); cur.w += 0.25f * bf2f(v.w);
    *(float4*)o = cur;
}

extern "C" void kernel_launch(void* const* d_in, const int* in_sizes, int n_in,
                              void* d_out, int out_size, void* d_ws, size_t ws_size,
                              hipStream_t stream)
{
    const float* emb  = (const float*)d_in[0];
    const int*   rows = (const int*)d_in[1];
    const int*   cols = (const int*)d_in[2];
    const float* vals = (const float*)d_in[3];
    const int*   node = (const int*)d_in[4];
    const int*   pos  = (const int*)d_in[5];
    const int*   neg  = (const int*)d_in[6];
    float* out = (float*)d_out;

    const int E = in_sizes[1];
    const int B = in_sizes[4];
    const int N = in_sizes[0] / 64;
    const size_t nd = (size_t)N * 64;
    const int chunkE = (E + NCHUNK - 1) / NCHUNK;
    const int nbucket = (N + BMASK) >> BSHIFT;     // 3125 for N=100000

    // workspace layout
    ushort* aggA        = (ushort*)d_ws;            // N*64 bf16
    ushort* aggB        = aggA + nd;                // N*64 bf16 (also emb cast)
    int2*  edges        = (int2*)(aggB + nd);       // E (bucket-grouped)
    int2*  edges2       = edges + E;                // E + 16 (row-sorted + pad)
    int*   cnt          = (int*)(edges2 + E + 16);  // NCHUNK * NBUCKET
    int*   totals       = cnt + (long)NCHUNK * NBUCKET;  // NBUCKET
    int*   bucket_start = totals + NBUCKET;         // NBUCKET+1
    int*   row_start    = bucket_start + NBUCKET + 1;    // nbucket*32+1
    // offs reuses edges2's storage (dead before sort_bkt writes edges2)
    int*   offs         = (int*)edges2;             // NCHUNK * NBUCKET

    const int gtotal   = 3 * B * 16;
    const int gblocks  = (gtotal + 255) / 256;
    const int cblocks  = ((int)(nd / 4) + 255) / 256;
    const int bblocks  = (nbucket + 255) / 256;     // 13
    const int rblocks  = (N + 3) / 4;               // spmm: 4 rows/block

    init_out_k<<<gblocks, 256, 0, stream>>>(emb, node, pos, neg, out, B);
    f2bf_k<<<cblocks, 256, 0, stream>>>(emb, aggB, (int)(nd / 4));

    // ---- bucketed partition + per-bucket counting sort; no global atomics ----
    count_k<<<NCHUNK, 1024, 0, stream>>>(rows, cnt, E, chunkE);
    localscan_k<<<bblocks, 256, 0, stream>>>(cnt, offs, totals);
    scan_fused_k<<<1, 1024, 0, stream>>>(totals, bucket_start, nbucket);
    scatter3_k<<<NCHUNK, 1024, 0, stream>>>(rows, cols, vals, offs, bucket_start, edges, E, chunkE);
    sort_bkt_k<<<nbucket, 256, 0, stream>>>(bucket_start, edges, edges2, row_start, nbucket);

    // ---- 3 propagation hops, row-wave register-accumulating spmm ----
    spmm_csr_k<<<rblocks, 256, 0, stream>>>(row_start, edges2, aggB, aggA, N);
    gather_add_k<<<gblocks, 256, 0, stream>>>(aggA, node, pos, neg, out, B);

    spmm_csr_k<<<rblocks, 256, 0, stream>>>(row_start, edges2, aggA, aggB, N);
    gather_add_k<<<gblocks, 256, 0, stream>>>(aggB, node, pos, neg, out, B);

    spmm_csr_k<<<rblocks, 256, 0, stream>>>(row_start, edges2, aggB, aggA, N);
    gather_add_k<<<gblocks, 256, 0, stream>>>(aggA, node, pos, neg, out, B);
}

// Round 15
// 211.011 us; speedup vs baseline: 1.1198x; 1.1198x over previous
//
#include <hip/hip_runtime.h>

// LightGCN 3-hop propagation, D=64, bf16 features / fp32 accumulate.
// R15: R14 had a one-line indexing bug (eB read row_start[rB+2] instead of
// row_start[rB+1] -> row B double-consumed the next row's segment, absmax 32).
// Fixed. Structure: DUAL-ROW waves — each wave owns two consecutive rows
// (contiguous edge segments); merged loop interleaves A/B s_loads and
// gathers (~2x memory ops in flight); cascade tails, no masking (R13 lesson:
// masked slots still fetch their lines).

#define NBUCKET 3125     // N=100000 rows, 32 per bucket
#define BSHIFT  5
#define BMASK   31
#define NCHUNK  256      // edge chunks; E=1.6M -> 6250 edges/chunk

static __device__ __forceinline__ ushort f2bf(float f) {
    unsigned u = __float_as_uint(f);
    unsigned r = (u + 0x7fffu + ((u >> 16) & 1u)) >> 16;   // RNE
    return (ushort)r;
}
static __device__ __forceinline__ float bf2f(ushort b) {
    return __uint_as_float(((unsigned)b) << 16);
}

__global__ __launch_bounds__(256) void f2bf_k(
    const float* __restrict__ in, ushort* __restrict__ out, int n4)
{
    int i = blockIdx.x * blockDim.x + threadIdx.x;
    if (i >= n4) return;
    float4 v = *(const float4*)(in + (long)i * 4);
    ushort4 o;
    o.x = f2bf(v.x); o.y = f2bf(v.y); o.z = f2bf(v.z); o.w = f2bf(v.w);
    *(ushort4*)(out + (long)i * 4) = o;
}

// pass A: per-chunk bucket histogram in LDS (no global atomics); 16 waves
__global__ __launch_bounds__(1024) void count_k(
    const int* __restrict__ rows, int* __restrict__ cnt, int E, int chunkE)
{
    __shared__ unsigned h[NBUCKET];
    int c = blockIdx.x;
    for (int b = threadIdx.x; b < NBUCKET; b += 1024) h[b] = 0u;
    __syncthreads();
    int s = c * chunkE;
    int e = min(s + chunkE, E);
    for (int j = s + (int)threadIdx.x; j < e; j += 1024)
        atomicAdd(&h[rows[j] >> BSHIFT], 1u);
    __syncthreads();
    int* o = cnt + (long)c * NBUCKET;
    for (int b = threadIdx.x; b < NBUCKET; b += 1024) o[b] = (int)h[b];
}

// pass B: per-bucket local exclusive prefix over chunks + bucket totals.
__global__ __launch_bounds__(256) void localscan_k(
    const int* __restrict__ cnt, int* __restrict__ offs,
    int* __restrict__ totals)
{
    int b = blockIdx.x * 256 + threadIdx.x;
    if (b >= NBUCKET) return;
    int run = 0;
    #pragma unroll 8
    for (int c = 0; c < NCHUNK; ++c) {
        long i = (long)c * NBUCKET + b;
        int v = cnt[i];
        offs[i] = run;
        run += v;
    }
    totals[b] = run;
}

// fused exclusive scan over nbucket elements; single block of 1024
__global__ __launch_bounds__(1024) void scan_fused_k(
    const int* __restrict__ totals, int* __restrict__ bucket_start, int nbucket)
{
    __shared__ int sm[1024];
    __shared__ int carry_s;
    if (threadIdx.x == 0) carry_s = 0;
    __syncthreads();
    int ntile = (nbucket + 1023) / 1024;
    for (int t = 0; t < ntile; ++t) {
        int i = t * 1024 + threadIdx.x;
        int v = (i < nbucket) ? totals[i] : 0;
        sm[threadIdx.x] = v;
        __syncthreads();
        for (int off = 1; off < 1024; off <<= 1) {
            int add = (threadIdx.x >= off) ? sm[threadIdx.x - off] : 0;
            __syncthreads();
            sm[threadIdx.x] += add;
            __syncthreads();
        }
        int c0 = carry_s;
        if (i < nbucket) bucket_start[i] = c0 + sm[threadIdx.x] - v;
        __syncthreads();
        if (threadIdx.x == 1023) carry_s = c0 + sm[1023];
        __syncthreads();
    }
    if (threadIdx.x == 0) bucket_start[nbucket] = carry_s;   // == E
}

// pass C: partition edges into bucket segments; LDS cursors only; 16 waves.
// edge payload: .x = (row&31)<<17 | col  (col < 2^17), .y = val bits
__global__ __launch_bounds__(1024) void scatter3_k(
    const int* __restrict__ rows, const int* __restrict__ cols,
    const float* __restrict__ vals, const int* __restrict__ offs,
    const int* __restrict__ bucket_start,
    int2* __restrict__ edges, int E, int chunkE)
{
    __shared__ int cur[NBUCKET];
    int c = blockIdx.x;
    const int* o = offs + (long)c * NBUCKET;
    for (int b = threadIdx.x; b < NBUCKET; b += 1024)
        cur[b] = o[b] + bucket_start[b];
    __syncthreads();
    int s = c * chunkE;
    int e = min(s + chunkE, E);
    for (int j = s + (int)threadIdx.x; j < e; j += 1024) {
        int r = rows[j];
        int pos = atomicAdd(&cur[r >> BSHIFT], 1);
        edges[pos] = make_int2(((r & BMASK) << 17) | cols[j],
                               __float_as_int(vals[j]));
    }
}

// pass D: per-bucket counting sort, one 256-thread block per bucket.
__global__ __launch_bounds__(256) void sort_bkt_k(
    const int* __restrict__ bucket_start, const int2* __restrict__ edges_in,
    int2* __restrict__ edges_out, int* __restrict__ row_start, int nbucket)
{
    __shared__ int cnt_s[32];
    __shared__ int cur_s[32];
    int bk = blockIdx.x;
    int t = (int)threadIdx.x;
    int s = bucket_start[bk];
    int e = bucket_start[bk + 1];
    if (t < 32) cnt_s[t] = 0;
    __syncthreads();
    for (int j = s + t; j < e; j += 256)
        atomicAdd(&cnt_s[(unsigned)edges_in[j].x >> 17], 1);
    __syncthreads();
    if (t == 0) {
        int run = s;
        #pragma unroll
        for (int r = 0; r < 32; ++r) {
            int c = cnt_s[r];
            cur_s[r] = run;
            row_start[bk * 32 + r] = run;
            run += c;
        }
    }
    __syncthreads();
    for (int j = s + t; j < e; j += 256) {
        int2 ed = edges_in[j];
        int pos = atomicAdd(&cur_s[(unsigned)ed.x >> 17], 1);
        edges_out[pos] = ed;
    }
    if (bk == nbucket - 1 && t == 0) row_start[nbucket * 32] = e;   // == E
}

#define GMA(nm, ee) float nm = __int_as_float(ee.y) * \
    bf2f(x[(long)(ee.x & 0x1FFFF) * 64 + d])

// spmm: one wave per TWO consecutive rows; lane = feature dim; scalar edge
// stream; merged loop interleaves A/B loads and gathers (2x in flight);
// cascade tails (no masking -> no wasted line fetches).
__global__ __launch_bounds__(256) void spmm_csr_k(
    const int* __restrict__ row_start, const int2* __restrict__ edges,
    const ushort* __restrict__ x, ushort* __restrict__ y, int N)
{
    int wid = __builtin_amdgcn_readfirstlane((int)(threadIdx.x >> 6));
    int p = blockIdx.x * 4 + wid;
    int rA = p * 2;
    if (rA >= N) return;
    int rB = rA + 1;
    int d = (int)(threadIdx.x & 63);
    int sA = row_start[rA];                 // consecutive -> merged s_load
    int eA = row_start[rA + 1];
    int eB = (rB < N) ? row_start[rB + 1] : eA;   // FIX: was rB+2 in R14
    int sB = eA;
    float aA0=0.f,aA1=0.f,aA2=0.f,aA3=0.f,aA4=0.f,aA5=0.f,aA6=0.f,aA7=0.f;
    float aB0=0.f,aB1=0.f,aB2=0.f,aB3=0.f,aB4=0.f,aB5=0.f,aB6=0.f,aB7=0.f;
    int jA = sA, jB = sB;
    while ((jA + 8 <= eA) || (jB + 8 <= eB)) {
        int doA = (jA + 8 <= eA);
        int doB = (jB + 8 <= eB);
        int2 A0,A1,A2,A3,A4,A5,A6,A7;
        int2 B0,B1,B2,B3,B4,B5,B6,B7;
        if (doA) {
            A0 = edges[jA];     A1 = edges[jA + 1];
            A2 = edges[jA + 2]; A3 = edges[jA + 3];
            A4 = edges[jA + 4]; A5 = edges[jA + 5];
            A6 = edges[jA + 6]; A7 = edges[jA + 7];
        }
        if (doB) {
            B0 = edges[jB];     B1 = edges[jB + 1];
            B2 = edges[jB + 2]; B3 = edges[jB + 3];
            B4 = edges[jB + 4]; B5 = edges[jB + 5];
            B6 = edges[jB + 6]; B7 = edges[jB + 7];
        }
        if (doA) {
            GMA(pA0, A0); GMA(pA1, A1); GMA(pA2, A2); GMA(pA3, A3);
            GMA(pA4, A4); GMA(pA5, A5); GMA(pA6, A6); GMA(pA7, A7);
            aA0 += pA0; aA1 += pA1; aA2 += pA2; aA3 += pA3;
            aA4 += pA4; aA5 += pA5; aA6 += pA6; aA7 += pA7;
            jA += 8;
        }
        if (doB) {
            GMA(pB0, B0); GMA(pB1, B1); GMA(pB2, B2); GMA(pB3, B3);
            GMA(pB4, B4); GMA(pB5, B5); GMA(pB6, B6); GMA(pB7, B7);
            aB0 += pB0; aB1 += pB1; aB2 += pB2; aB3 += pB3;
            aB4 += pB4; aB5 += pB5; aB6 += pB6; aB7 += pB7;
            jB += 8;
        }
    }
    // tails (remainder < 8 each): 4/2/1 cascade, A then B
    if (jA + 4 <= eA) {
        int2 A0 = edges[jA], A1 = edges[jA+1], A2 = edges[jA+2], A3 = edges[jA+3];
        GMA(pA0, A0); GMA(pA1, A1); GMA(pA2, A2); GMA(pA3, A3);
        aA0 += pA0; aA1 += pA1; aA2 += pA2; aA3 += pA3;
        jA += 4;
    }
    if (jB + 4 <= eB) {
        int2 B0 = edges[jB], B1 = edges[jB+1], B2 = edges[jB+2], B3 = edges[jB+3];
        GMA(pB0, B0); GMA(pB1, B1); GMA(pB2, B2); GMA(pB3, B3);
        aB0 += pB0; aB1 += pB1; aB2 += pB2; aB3 += pB3;
        jB += 4;
    }
    if (jA + 2 <= eA) {
        int2 A0 = edges[jA], A1 = edges[jA+1];
        GMA(pA0, A0); GMA(pA1, A1);
        aA0 += pA0; aA1 += pA1;
        jA += 2;
    }
    if (jB + 2 <= eB) {
        int2 B0 = edges[jB], B1 = edges[jB+1];
        GMA(pB0, B0); GMA(pB1, B1);
        aB0 += pB0; aB1 += pB1;
        jB += 2;
    }
    if (jA < eA) {
        int2 A0 = edges[jA];
        GMA(pA0, A0);
        aA0 += pA0;
    }
    if (jB < eB) {
        int2 B0 = edges[jB];
        GMA(pB0, B0);
        aB0 += pB0;
    }
    float sumA = ((aA0 + aA1) + (aA2 + aA3)) + ((aA4 + aA5) + (aA6 + aA7));
    y[(long)rA * 64 + d] = f2bf(sumA);
    if (rB < N) {
        float sumB = ((aB0 + aB1) + (aB2 + aB3)) + ((aB4 + aB5) + (aB6 + aB7));
        y[(long)rB * 64 + d] = f2bf(sumB);
    }
}

// out[0..2] = 0.25*emb[idx] (hop-0 term), out[3..5] = emb[idx]; float4 lanes
__global__ __launch_bounds__(256) void init_out_k(
    const float* __restrict__ emb, const int* __restrict__ n0,
    const int* __restrict__ n1, const int* __restrict__ n2,
    float* __restrict__ out, int B)
{
    int tid = blockIdx.x * blockDim.x + threadIdx.x;
    int total = 3 * B * 16;                 // float4 granularity
    if (tid >= total) return;
    int arr = tid / (B * 16);
    int rem = tid - arr * (B * 16);
    int b = rem >> 4;
    int d4 = rem & 15;
    const int* __restrict__ idx = (arr == 0) ? n0 : ((arr == 1) ? n1 : n2);
    float4 v = *(const float4*)(emb + (long)idx[b] * 64 + d4 * 4);
    float4 q = make_float4(0.25f * v.x, 0.25f * v.y, 0.25f * v.z, 0.25f * v.w);
    *(float4*)(out + (long)arr * B * 64 + (long)rem * 4) = q;
    *(float4*)(out + (long)(arr + 3) * B * 64 + (long)rem * 4) = v;
}

// pooled += 0.25 * agg_bf16[idx]
__global__ __launch_bounds__(256) void gather_add_k(
    const ushort* __restrict__ agg, const int* __restrict__ n0,
    const int* __restrict__ n1, const int* __restrict__ n2,
    float* __restrict__ out, int B)
{
    int tid = blockIdx.x * blockDim.x + threadIdx.x;
    int total = 3 * B * 16;
    if (tid >= total) return;
    int arr = tid / (B * 16);
    int rem = tid - arr * (B * 16);
    int b = rem >> 4;
    int d4 = rem & 15;
    const int* __restrict__ idx = (arr == 0) ? n0 : ((arr == 1) ? n1 : n2);
    ushort4 v = *(const ushort4*)(agg + (long)idx[b] * 64 + d4 * 4);
    float* o = out + (long)arr * B * 64 + (long)rem * 4;
    float4 cur = *(float4*)o;
    cur.x += 0.25f * bf2f(v.x); cur.y += 0.25f * bf2f(v.y);
    cur.z += 0.25f * bf2f(v.z); cur.w += 0.25f * bf2f(v.w);
    *(float4*)o = cur;
}

extern "C" void kernel_launch(void* const* d_in, const int* in_sizes, int n_in,
                              void* d_out, int out_size, void* d_ws, size_t ws_size,
                              hipStream_t stream)
{
    const float* emb  = (const float*)d_in[0];
    const int*   rows = (const int*)d_in[1];
    const int*   cols = (const int*)d_in[2];
    const float* vals = (const float*)d_in[3];
    const int*   node = (const int*)d_in[4];
    const int*   pos  = (const int*)d_in[5];
    const int*   neg  = (const int*)d_in[6];
    float* out = (float*)d_out;

    const int E = in_sizes[1];
    const int B = in_sizes[4];
    const int N = in_sizes[0] / 64;
    const size_t nd = (size_t)N * 64;
    const int chunkE = (E + NCHUNK - 1) / NCHUNK;
    const int nbucket = (N + BMASK) >> BSHIFT;     // 3125 for N=100000

    // workspace layout
    ushort* aggA        = (ushort*)d_ws;            // N*64 bf16
    ushort* aggB        = aggA + nd;                // N*64 bf16 (also emb cast)
    int2*  edges        = (int2*)(aggB + nd);       // E (bucket-grouped)
    int2*  edges2       = edges + E;                // E (row-sorted)
    int*   cnt          = (int*)(edges2 + E);       // NCHUNK * NBUCKET
    int*   totals       = cnt + (long)NCHUNK * NBUCKET;  // NBUCKET
    int*   bucket_start = totals + NBUCKET;         // NBUCKET+1
    int*   row_start    = bucket_start + NBUCKET + 1;    // nbucket*32+1
    // offs reuses edges2's storage (dead before sort_bkt writes edges2)
    int*   offs         = (int*)edges2;             // NCHUNK * NBUCKET

    const int gtotal   = 3 * B * 16;
    const int gblocks  = (gtotal + 255) / 256;
    const int cblocks  = ((int)(nd / 4) + 255) / 256;
    const int bblocks  = (nbucket + 255) / 256;     // 13
    const int npair    = (N + 1) / 2;
    const int rblocks  = (npair + 3) / 4;           // spmm: 4 row-pairs/block

    init_out_k<<<gblocks, 256, 0, stream>>>(emb, node, pos, neg, out, B);
    f2bf_k<<<cblocks, 256, 0, stream>>>(emb, aggB, (int)(nd / 4));

    // ---- bucketed partition + per-bucket counting sort; no global atomics ----
    count_k<<<NCHUNK, 1024, 0, stream>>>(rows, cnt, E, chunkE);
    localscan_k<<<bblocks, 256, 0, stream>>>(cnt, offs, totals);
    scan_fused_k<<<1, 1024, 0, stream>>>(totals, bucket_start, nbucket);
    scatter3_k<<<NCHUNK, 1024, 0, stream>>>(rows, cols, vals, offs, bucket_start, edges, E, chunkE);
    sort_bkt_k<<<nbucket, 256, 0, stream>>>(bucket_start, edges, edges2, row_start, nbucket);

    // ---- 3 propagation hops, dual-row wave spmm ----
    spmm_csr_k<<<rblocks, 256, 0, stream>>>(row_start, edges2, aggB, aggA, N);
    gather_add_k<<<gblocks, 256, 0, stream>>>(aggA, node, pos, neg, out, B);

    spmm_csr_k<<<rblocks, 256, 0, stream>>>(row_start, edges2, aggA, aggB, N);
    gather_add_k<<<gblocks, 256, 0, stream>>>(aggB, node, pos, neg, out, B);

    spmm_csr_k<<<rblocks, 256, 0, stream>>>(row_start, edges2, aggB, aggA, N);
    gather_add_k<<<gblocks, 256, 0, stream>>>(aggA, node, pos, neg, out, B);
}